// Round 5
// baseline (25.019 us; speedup 1.0000x reference)
//
#include <hip/hip_runtime.h>
#include <math.h>

#pragma clang fp contract(off)

#define NPTS 4096
#define NC   20
#define NK   6
#define NM   3
#define NG   (NK*NM)
#define RES  48
#define NPIX (RES*RES)
#define NSAMP 16
#define TS   8                       // tile side (pixels)
#define TPG  (RES/TS)                // 6 tiles per axis
#define NTIL (TPG*TPG)               // 36 tiles per g
#define NSL  8                       // point slices = waves per block
#define SLPTS (NPTS/NSL)             // 512 points per slice
#define BT   (NSL*64)                // 512 threads per tile block
#define PPT  (NPTS/BT)               // 8 points per thread (phase A)

// ---------------- kernel 1 (tiny, fully parallel): top-2 features + trig ----------------
// blocks 0..15: top-2 of 20 feats per point (order-independent max-chain).
// block 16: the 12 f64-trig values (sin/cos of theta/phi, rounded to f32 — matches
// numpy's f32 sin/cos closely; same code as all previous passing rounds).
__global__ void k_pre(const float* __restrict__ feats, const float* __restrict__ theta,
                      const float* __restrict__ phi,
                      float* __restrict__ trig, float2* __restrict__ pt2) {
  int b = blockIdx.x, t = threadIdx.x;
  if (b == 16) {
    if (t < 12) {
      int m = t >> 2, w = t & 3;
      double a = (w < 2) ? (double)theta[m] : (double)phi[m];
      double r = (w & 1) ? cos(a) : sin(a);
      trig[m*4 + w] = (float)r;      // [sin th, cos th, sin ph, cos ph]
    }
    return;
  }
  int n = b*256 + t;
  const float4* f4 = (const float4*)(feats + n*NC);   // 20 floats = 5 float4, 16B-aligned
  float m1 = -INFINITY, m2 = -INFINITY;
  #pragma unroll
  for (int q = 0; q < 5; ++q) {
    float4 f = f4[q];
    float e[4] = {f.x, f.y, f.z, f.w};
    #pragma unroll
    for (int j = 0; j < 4; ++j) {
      float v = e[j];
      if (v > m1) { m2 = m1; m1 = v; }
      else if (v > m2) { m2 = v; }
    }
  }
  pt2[n] = make_float2(m2, m1);      // (2nd largest, largest) = sort(...)[ -2: ]
}

// ---------------- mega kernel: per-(tile,g) block does EVERYTHING ----------------
// Phase A: proj + validity + exact min/max (order-free!) -> cs  (redundant per block)
// Phase B: normalize all 4096 coords into LDS (invalid -> 1e30)
// Phase C: halo-cull scan, 8 point-slices, first-16-by-index per pixel
// Phase D: capped-prefix merge across slices + occ/softmax + write
__global__ void __launch_bounds__(BT, 4) k_mega(const float* __restrict__ xyz,
    const float* __restrict__ boxes, const float* __restrict__ trig,
    const float2* __restrict__ pt2, float* __restrict__ out) {
  int tile = blockIdx.x, g = blockIdx.y;
  int k = g / NM, m = g - k * NM;
  int t = threadIdx.x, w = t >> 6, lane = t & 63;

  __shared__ float2 spts[NPTS];                    // 32 KiB normalized coords
  __shared__ unsigned short sidx[NSL][64][NSAMP+1];// padded vs bank pattern
  __shared__ unsigned char scnt[NSL][64];
  __shared__ float cred[NSL][4];
  __shared__ float csh[4];

  // uniform scalars
  float st = trig[4*m+0], ct = trig[4*m+1], sp = trig[4*m+2], cp = trig[4*m+3];
  float cxc = ct*cp, cyc = st*cp, czc = sp;        // sphere center (r=1)
  float b0 = boxes[k*6+0], b1 = boxes[k*6+1], b2 = boxes[k*6+2];
  float b3 = boxes[k*6+3], b4 = boxes[k*6+4], b5 = boxes[k*6+5];

  // ---- phase A: project + validity + min/max ----
  float uu[PPT], vv[PPT];
  unsigned vbits = 0;
  float mn0 = INFINITY, mn1 = INFINITY, mx0 = -INFINITY, mx1 = -INFINITY;
  #pragma unroll
  for (int i = 0; i < PPT; ++i) {
    int n = t + i*BT;
    float x = xyz[n*3+0], y = xyz[n*3+1], z = xyz[n*3+2];
    float dx = x - cxc, dy = y - cyc, dz = z - czc;
    float u = dx*(-st) + dy*ct;                    // U = [-st, ct, 0]
    float v = (dx*(ct*sp) + dy*(st*sp)) + dz*cp;   // V = [ct*sp, st*sp, cp]
    uu[i] = u; vv[i] = v;
    bool val = (x >= b0) && (y >= b1) && (z >= b2) &&
               (x <= b3) && (y <= b4) && (z <= b5);
    if (val) {
      vbits |= (1u << i);
      mn0 = fminf(mn0,u); mx0 = fmaxf(mx0,u);
      mn1 = fminf(mn1,v); mx1 = fmaxf(mx1,v);
    }
  }
  #pragma unroll
  for (int off = 1; off < 64; off <<= 1) {
    mn0 = fminf(mn0, __shfl_xor(mn0, off)); mx0 = fmaxf(mx0, __shfl_xor(mx0, off));
    mn1 = fminf(mn1, __shfl_xor(mn1, off)); mx1 = fmaxf(mx1, __shfl_xor(mx1, off));
  }
  if (lane == 0) { cred[w][0]=mn0; cred[w][1]=mn1; cred[w][2]=mx0; cred[w][3]=mx1; }
  __syncthreads();
  if (t == 0) {
    float a0=cred[0][0], a1=cred[0][1], a2=cred[0][2], a3=cred[0][3];
    #pragma unroll
    for (int ww = 1; ww < NSL; ++ww) {
      a0 = fminf(a0, cred[ww][0]); a1 = fminf(a1, cred[ww][1]);
      a2 = fmaxf(a2, cred[ww][2]); a3 = fmaxf(a3, cred[ww][3]);
    }
    csh[0] = (a2 + a0) / 2.0f;
    csh[1] = (a3 + a1) / 2.0f;
    csh[2] = fmaxf(a2 - a0, 1e-5f) / 2.0f;
    csh[3] = fmaxf(a3 - a1, 1e-5f) / 2.0f;
  }
  __syncthreads();

  // ---- phase B: normalize into LDS (jax op order, identical to prior rounds) ----
  {
    float c0=csh[0], c1=csh[1], s0=csh[2], s1=csh[3];
    #pragma unroll
    for (int i = 0; i < PPT; ++i) {
      int n = t + i*BT;
      float2 o;
      if ((vbits >> i) & 1u) {
        float u = uu[i], v = vv[i];
        u = (u - c0) / s0; u = u + 1.0f; u = u * 0.8f; u = u * (float)RES; u = u / 2.0f; u = u + 0.1f*(float)RES;
        v = (v - c1) / s1; v = v + 1.0f; v = v * 0.8f; v = v * (float)RES; v = v / 2.0f; v = v + 0.1f*(float)RES;
        o = make_float2(u, v);
      } else {
        o = make_float2(1e30f, 1e30f);
      }
      spts[n] = o;
    }
  }
  __syncthreads();

  // ---- phase C: halo-cull scan (wave = 8x8 pixel tile, slice = 512 points) ----
  int ti = tile / TPG, tj = tile - (tile / TPG) * TPG;
  float si = (float)(ti*TS + (lane >> 3));
  float sj = (float)(tj*TS + (lane & 7));
  float lo0 = (float)(ti*TS) - 3.0f, hi0 = (float)(ti*TS + TS - 1) + 3.0f;
  float lo1 = (float)(tj*TS) - 3.0f, hi1 = (float)(tj*TS + TS - 1) + 3.0f;

  int cnt = 0;
  int base0 = w * SLPTS;
  for (int c = 0; c < SLPTS/64; ++c) {             // 8 chunks of 64 points
    int base = base0 + c*64;
    float2 pl = spts[base + lane];                 // lane's own point (cull test)
    bool cand = (pl.x >= lo0) && (pl.x <= hi0) && (pl.y >= lo1) && (pl.y <= hi1);
    unsigned long long msk = __ballot(cand);
    while (msk) {                                  // wave-uniform walk, ascending index
      int jj = __builtin_ctzll(msk);
      msk &= msk - 1ull;
      int n = base + jj;
      float2 pq = spts[n];                         // broadcast read
      float dx = si - pq.x, dy = sj - pq.y;
      float d2 = dx*dx + dy*dy;
      if (d2 < 9.0f && cnt < NSAMP) {
        sidx[w][lane][cnt] = (unsigned short)n;
        ++cnt;
      }
    }
    if (__all(cnt >= NSAMP)) break;                // per-slice early exit
  }
  scnt[w][lane] = (unsigned char)cnt;
  __syncthreads();

  // ---- phase D: merge (8 lanes per pixel, ranks q, q+8, ...) ----
  int p = t >> 3, q = t & 7;
  int tt[NSL+1]; tt[0] = 0;
  #pragma unroll
  for (int ww = 0; ww < NSL; ++ww) {
    int s2 = tt[ww] + (int)scnt[ww][p];
    tt[ww+1] = s2 > NSAMP ? NSAMP : s2;
  }
  float sum0 = 0.f, sum1 = 0.f, occ0 = 0.f, occ1 = 0.f;
  for (int r = q; r < tt[NSL]; r += 8) {
    int wsel = 0, i2 = r;
    #pragma unroll
    for (int ww = 1; ww < NSL; ++ww) if (r >= tt[ww]) { wsel = ww; i2 = r - tt[ww]; }
    int n = sidx[wsel][p][i2];
    float2 f = pt2[n];
    sum0 += f.x; sum1 += f.y;
    occ0 += (f.x != 0.f) ? 1.f : 0.f;
    occ1 += (f.y != 0.f) ? 1.f : 0.f;
  }
  sum0 += __shfl_xor(sum0,1); sum0 += __shfl_xor(sum0,2); sum0 += __shfl_xor(sum0,4);
  sum1 += __shfl_xor(sum1,1); sum1 += __shfl_xor(sum1,2); sum1 += __shfl_xor(sum1,4);
  occ0 += __shfl_xor(occ0,1); occ0 += __shfl_xor(occ0,2); occ0 += __shfl_xor(occ0,4);
  occ1 += __shfl_xor(occ1,1); occ1 += __shfl_xor(occ1,2); occ1 += __shfl_xor(occ1,4);

  if (q == 0) {
    float o0 = (occ0 == 0.f) ? 1.f : occ0;
    float o1 = (occ1 == 0.f) ? 1.f : occ1;
    float nf0 = sum0 / o0, nf1 = sum1 / o1;
    float mxv = fmaxf(nf0, nf1);
    float e0 = expf(nf0 - mxv), e1 = expf(nf1 - mxv);
    float a1 = e1 / (e0 + e1);
    float val = (nf0 == nf1) ? 0.f : a1 * 255.f;   // empty -> [1,0] -> channel1 = 0
    int pi = ti*TS + (p >> 3), pj = tj*TS + (p & 7);
    int base2 = g*3*NPIX + pi*RES + pj;
    out[base2] = val;
    out[base2 + NPIX] = val;
    out[base2 + 2*NPIX] = val;
  }
}

extern "C" void kernel_launch(void* const* d_in, const int* in_sizes, int n_in,
                              void* d_out, int out_size, void* d_ws, size_t ws_size,
                              hipStream_t stream) {
  const float* xyz   = (const float*)d_in[0];
  const float* feats = (const float*)d_in[1];
  const float* boxes = (const float*)d_in[2];
  const float* theta = (const float*)d_in[3];
  const float* phi   = (const float*)d_in[4];
  float* out = (float*)d_out;

  // ws layout (bytes): trig 0..48 (12 f32, padded to 64), pt2 64..32832 (NPTS float2)
  char* ws = (char*)d_ws;
  float*  trig = (float*)ws;
  float2* pt2  = (float2*)(ws + 64);

  k_pre<<<17, 256, 0, stream>>>(feats, theta, phi, trig, pt2);
  k_mega<<<dim3(NTIL, NG), BT, 0, stream>>>(xyz, boxes, trig, pt2, out);
}

// Round 6
// 24.908 us; speedup vs baseline: 1.0045x; 1.0045x over previous
//
#include <hip/hip_runtime.h>
#include <math.h>

#pragma clang fp contract(off)

#define NPTS 4096
#define NC   20
#define NK   6
#define NM   3
#define NG   (NK*NM)
#define RES  48
#define NPIX (RES*RES)
#define NSAMP 16
#define TS   8                       // tile side (pixels)
#define TPG  (RES/TS)                // 6 tiles per axis
#define NTIL (TPG*TPG)               // 36 tiles per g
#define NSL  8                       // point slices = waves per block
#define SLPTS (NPTS/NSL)             // 512 points per slice
#define BT   (NSL*64)                // 512 threads per block
#define CPS  (SLPTS/64)              // 8 chunks per slice (also = points per thread)

// Single kernel: each block owns one (8x8 pixel tile, g) pair and does everything.
// Phase A: per-thread projection+validity of ITS OWN 8 scan-points (registers), exact
//          order-free min/max reduction -> center/scale (redundant per block — cheap).
// Phase B: in-register normalization (invalid -> 1e30).
// Phase C: halo-cull scan; candidate coords fetched from owning lane via __shfl
//          (no LDS on the critical path), first-16-by-index per pixel -> sidx.
// Phase D: capped-prefix merge across the 8 slices; top-2 features computed inline
//          for the <=2 selected points per thread; occ/softmax; write.
__global__ void __launch_bounds__(BT) k_all(const float* __restrict__ xyz,
    const float* __restrict__ feats, const float* __restrict__ boxes,
    const float* __restrict__ theta, const float* __restrict__ phi,
    float* __restrict__ out) {
  int tile = blockIdx.x, g = blockIdx.y;
  int k = g / NM, m = g - k * NM;
  int t = threadIdx.x, w = t >> 6, lane = t & 63;

  __shared__ float trig_s[4];
  __shared__ unsigned short sidx[NSL][64][NSAMP+1];  // padded vs bank pattern
  __shared__ unsigned char scnt[NSL][64];
  __shared__ float cred[NSL][4];
  __shared__ float csh[4];

  // per-block f64 trig (matches numpy f32 sin/cos via round-from-double; as all rounds)
  if (t < 4) {
    double a = (t < 2) ? (double)theta[m] : (double)phi[m];
    double r = (t & 1) ? cos(a) : sin(a);
    trig_s[t] = (float)r;            // [sin th, cos th, sin ph, cos ph]
  }
  __syncthreads();
  float st = trig_s[0], ct = trig_s[1], sp = trig_s[2], cp = trig_s[3];
  float cxc = ct*cp, cyc = st*cp, czc = sp;          // sphere center (r=1)
  float b0 = boxes[k*6+0], b1 = boxes[k*6+1], b2 = boxes[k*6+2];
  float b3 = boxes[k*6+3], b4 = boxes[k*6+4], b5 = boxes[k*6+5];

  // ---- phase A: project + validity + min/max (thread owns its scan points) ----
  float pu[CPS], pv[CPS];
  unsigned vbits = 0;
  float mn0 = INFINITY, mn1 = INFINITY, mx0 = -INFINITY, mx1 = -INFINITY;
  #pragma unroll
  for (int i = 0; i < CPS; ++i) {
    int n = w*SLPTS + i*64 + lane;
    float x = xyz[n*3+0], y = xyz[n*3+1], z = xyz[n*3+2];
    float dx = x - cxc, dy = y - cyc, dz = z - czc;
    float u = dx*(-st) + dy*ct;                      // U = [-st, ct, 0]
    float v = (dx*(ct*sp) + dy*(st*sp)) + dz*cp;     // V = [ct*sp, st*sp, cp]
    pu[i] = u; pv[i] = v;
    bool val = (x >= b0) && (y >= b1) && (z >= b2) &&
               (x <= b3) && (y <= b4) && (z <= b5);
    if (val) {
      vbits |= (1u << i);
      mn0 = fminf(mn0,u); mx0 = fmaxf(mx0,u);
      mn1 = fminf(mn1,v); mx1 = fmaxf(mx1,v);
    }
  }
  #pragma unroll
  for (int off = 1; off < 64; off <<= 1) {
    mn0 = fminf(mn0, __shfl_xor(mn0, off)); mx0 = fmaxf(mx0, __shfl_xor(mx0, off));
    mn1 = fminf(mn1, __shfl_xor(mn1, off)); mx1 = fmaxf(mx1, __shfl_xor(mx1, off));
  }
  if (lane == 0) { cred[w][0]=mn0; cred[w][1]=mn1; cred[w][2]=mx0; cred[w][3]=mx1; }
  __syncthreads();
  if (t == 0) {
    float a0=cred[0][0], a1=cred[0][1], a2=cred[0][2], a3=cred[0][3];
    #pragma unroll
    for (int ww = 1; ww < NSL; ++ww) {
      a0 = fminf(a0, cred[ww][0]); a1 = fminf(a1, cred[ww][1]);
      a2 = fmaxf(a2, cred[ww][2]); a3 = fmaxf(a3, cred[ww][3]);
    }
    csh[0] = (a2 + a0) / 2.0f;
    csh[1] = (a3 + a1) / 2.0f;
    csh[2] = fmaxf(a2 - a0, 1e-5f) / 2.0f;
    csh[3] = fmaxf(a3 - a1, 1e-5f) / 2.0f;
  }
  __syncthreads();

  // ---- phase B: normalize in registers (jax op order, identical to prior rounds) ----
  {
    float c0=csh[0], c1=csh[1], s0=csh[2], s1=csh[3];
    #pragma unroll
    for (int i = 0; i < CPS; ++i) {
      if ((vbits >> i) & 1u) {
        float u = pu[i], v = pv[i];
        u = (u - c0) / s0; u = u + 1.0f; u = u * 0.8f; u = u * (float)RES; u = u / 2.0f; u = u + 0.1f*(float)RES;
        v = (v - c1) / s1; v = v + 1.0f; v = v * 0.8f; v = v * (float)RES; v = v / 2.0f; v = v + 0.1f*(float)RES;
        pu[i] = u; pv[i] = v;
      } else {
        pu[i] = 1e30f; pv[i] = 1e30f;
      }
    }
  }

  // ---- phase C: halo-cull scan; candidates via __shfl from owning lane ----
  int ti = tile / TPG, tj = tile - (tile / TPG) * TPG;
  float si = (float)(ti*TS + (lane >> 3));
  float sj = (float)(tj*TS + (lane & 7));
  float lo0 = (float)(ti*TS) - 3.0f, hi0 = (float)(ti*TS + TS - 1) + 3.0f;
  float lo1 = (float)(tj*TS) - 3.0f, hi1 = (float)(tj*TS + TS - 1) + 3.0f;

  int cnt = 0;
  bool done = false;
  // manual unroll so pu[c]/pv[c] stay compile-time-indexed (registers, not scratch)
  #define CHUNK(c)                                                              \
  if (!done) {                                                                  \
    float px = pu[c], py = pv[c];                                               \
    bool cand = (px >= lo0) && (px <= hi0) && (py >= lo1) && (py <= hi1);       \
    unsigned long long msk = __ballot(cand);                                    \
    int base = w*SLPTS + (c)*64;                                                \
    while (msk) {                                                               \
      int j0 = __builtin_ctzll(msk); msk &= msk - 1ull;                         \
      int j1 = j0, j2 = j0, j3 = j0, have = 1;                                  \
      if (msk) { j1 = __builtin_ctzll(msk); msk &= msk - 1ull; have = 2;        \
        if (msk) { j2 = __builtin_ctzll(msk); msk &= msk - 1ull; have = 3;      \
          if (msk) { j3 = __builtin_ctzll(msk); msk &= msk - 1ull; have = 4; }}}\
      float x0 = __shfl(px, j0), y0 = __shfl(py, j0);                           \
      float x1 = __shfl(px, j1), y1 = __shfl(py, j1);                           \
      float x2 = __shfl(px, j2), y2 = __shfl(py, j2);                           \
      float x3 = __shfl(px, j3), y3 = __shfl(py, j3);                           \
      float dx, dy, d2;                                                         \
      dx = si - x0; dy = sj - y0; d2 = dx*dx + dy*dy;                           \
      if (d2 < 9.0f && cnt < NSAMP) { sidx[w][lane][cnt] = (unsigned short)(base + j0); ++cnt; } \
      if (have > 1) { dx = si - x1; dy = sj - y1; d2 = dx*dx + dy*dy;           \
        if (d2 < 9.0f && cnt < NSAMP) { sidx[w][lane][cnt] = (unsigned short)(base + j1); ++cnt; } } \
      if (have > 2) { dx = si - x2; dy = sj - y2; d2 = dx*dx + dy*dy;           \
        if (d2 < 9.0f && cnt < NSAMP) { sidx[w][lane][cnt] = (unsigned short)(base + j2); ++cnt; } } \
      if (have > 3) { dx = si - x3; dy = sj - y3; d2 = dx*dx + dy*dy;           \
        if (d2 < 9.0f && cnt < NSAMP) { sidx[w][lane][cnt] = (unsigned short)(base + j3); ++cnt; } } \
    }                                                                           \
    if (__all(cnt >= NSAMP)) done = true;                                       \
  }
  CHUNK(0) CHUNK(1) CHUNK(2) CHUNK(3) CHUNK(4) CHUNK(5) CHUNK(6) CHUNK(7)
  #undef CHUNK
  scnt[w][lane] = (unsigned char)cnt;
  __syncthreads();

  // ---- phase D: merge (8 lanes/pixel), inline top-2 features, softmax, write ----
  int p = t >> 3, q = t & 7;
  int tt[NSL+1]; tt[0] = 0;
  #pragma unroll
  for (int ww = 0; ww < NSL; ++ww) {
    int s2 = tt[ww] + (int)scnt[ww][p];
    tt[ww+1] = s2 > NSAMP ? NSAMP : s2;
  }
  float sum0 = 0.f, sum1 = 0.f, occ0 = 0.f, occ1 = 0.f;
  for (int r = q; r < tt[NSL]; r += 8) {
    int wsel = 0, i2 = r;
    #pragma unroll
    for (int ww = 1; ww < NSL; ++ww) if (r >= tt[ww]) { wsel = ww; i2 = r - tt[ww]; }
    int n = sidx[wsel][p][i2];
    // top-2 of the 20 features (same max-chain as before -> identical values)
    const float4* f4 = (const float4*)(feats + n*NC);  // 80 B, 16B-aligned
    float m1 = -INFINITY, m2 = -INFINITY;
    #pragma unroll
    for (int qq = 0; qq < 5; ++qq) {
      float4 f = f4[qq];
      float e0 = f.x, e1 = f.y, e2 = f.z, e3 = f.w;
      if (e0 > m1) { m2 = m1; m1 = e0; } else if (e0 > m2) { m2 = e0; }
      if (e1 > m1) { m2 = m1; m1 = e1; } else if (e1 > m2) { m2 = e1; }
      if (e2 > m1) { m2 = m1; m1 = e2; } else if (e2 > m2) { m2 = e2; }
      if (e3 > m1) { m2 = m1; m1 = e3; } else if (e3 > m2) { m2 = e3; }
    }
    sum0 += m2; sum1 += m1;
    occ0 += (m2 != 0.f) ? 1.f : 0.f;
    occ1 += (m1 != 0.f) ? 1.f : 0.f;
  }
  sum0 += __shfl_xor(sum0,1); sum0 += __shfl_xor(sum0,2); sum0 += __shfl_xor(sum0,4);
  sum1 += __shfl_xor(sum1,1); sum1 += __shfl_xor(sum1,2); sum1 += __shfl_xor(sum1,4);
  occ0 += __shfl_xor(occ0,1); occ0 += __shfl_xor(occ0,2); occ0 += __shfl_xor(occ0,4);
  occ1 += __shfl_xor(occ1,1); occ1 += __shfl_xor(occ1,2); occ1 += __shfl_xor(occ1,4);

  if (q == 0) {
    float o0 = (occ0 == 0.f) ? 1.f : occ0;
    float o1 = (occ1 == 0.f) ? 1.f : occ1;
    float nf0 = sum0 / o0, nf1 = sum1 / o1;
    float mxv = fmaxf(nf0, nf1);
    float e0 = expf(nf0 - mxv), e1 = expf(nf1 - mxv);
    float a1 = e1 / (e0 + e1);
    float val = (nf0 == nf1) ? 0.f : a1 * 255.f;   // empty -> [1,0] -> channel1 = 0
    int pi = ti*TS + (p >> 3), pj = tj*TS + (p & 7);
    int base2 = g*3*NPIX + pi*RES + pj;
    out[base2] = val;
    out[base2 + NPIX] = val;
    out[base2 + 2*NPIX] = val;
  }
}

extern "C" void kernel_launch(void* const* d_in, const int* in_sizes, int n_in,
                              void* d_out, int out_size, void* d_ws, size_t ws_size,
                              hipStream_t stream) {
  const float* xyz   = (const float*)d_in[0];
  const float* feats = (const float*)d_in[1];
  const float* boxes = (const float*)d_in[2];
  const float* theta = (const float*)d_in[3];
  const float* phi   = (const float*)d_in[4];
  float* out = (float*)d_out;
  (void)d_ws; (void)ws_size;

  k_all<<<dim3(NTIL, NG), BT, 0, stream>>>(xyz, feats, boxes, theta, phi, out);
}